// Round 10
// baseline (11871.200 us; speedup 1.0000x reference)
//
#include <hip/hip_runtime.h>

#define Bn 4096
#define Tn 256
#define NZ 64
#define Hn 512
#define INn 68
#define DPRv 24.0f
#define MB 32
#define NWAVE 16
#define NTHREADS 1024
#define NBLK 128

// unified per-wave weight stream: 16 waves x 37 groups (32 h + 5 ext) x 5 frags x 64 lanes x 8 shorts
#define NGRP 37
#define FRAGS 5
#define WAVE_S8 (NGRP * FRAGS * 64)         /* short8 units per wave: 11840 */
#define STREAM_SHORTS (NWAVE * WAVE_S8 * 8) /* 1,515,520 (3.03 MB) */

typedef short short8 __attribute__((ext_vector_type(8)));
typedef float floatx16 __attribute__((ext_vector_type(16)));

__device__ __forceinline__ unsigned short f2bf(float f) {
  unsigned int u = __float_as_uint(f);
  u += 0x7FFFu + ((u >> 16) & 1u);
  return (unsigned short)(u >> 16);
}
__device__ __forceinline__ float fsig(float x) {
  return __builtin_amdgcn_rcpf(1.0f + __builtin_amdgcn_exp2f(x * -1.4426950408889634f));
}
__device__ __forceinline__ float ftanh(float x) {
  return 1.0f - 2.0f * __builtin_amdgcn_rcpf(1.0f + __builtin_amdgcn_exp2f(x * 2.8853900817779268f));
}

// Pack weights (bf16) for the 16-wave slicing. Wave w owns hidden cols [w*32, w*32+32).
// Group gi<32 (K-slice gi of h): frag 0 -> W1 rows w*32+l31; frag 1..4 -> gate g=f-1,
//   W_hh row g*512 + w*32 + l31. Group gi>=32 (ext K-slice): frag 0 -> ZERO;
//   frag 1..4 -> W_ih rearranged cols [noise 0..63][gap0][gap1][dp=0][clus][pad..79].
__global__ void prep_pack(const float* __restrict__ Wih, const float* __restrict__ Whh,
                          const float* __restrict__ W1u, unsigned short* __restrict__ us) {
  const int idx = blockIdx.x * blockDim.x + threadIdx.x;
  if (idx >= STREAM_SHORTS / 8) return;
  const int lane = idx & 63;
  const int fragid = idx >> 6;
  const int f = fragid % FRAGS;
  const int gi = (fragid / FRAGS) % NGRP;
  const int w = fragid / (FRAGS * NGRP);
  const int l31 = lane & 31, half = lane >> 5;
  unsigned short v8[8];
  if (gi < 32) {
    const int k0 = gi * 16 + half * 8;
    if (f == 0) {
      const int n = w * 32 + l31;
#pragma unroll
      for (int j = 0; j < 8; ++j) v8[j] = f2bf(W1u[n * Hn + k0 + j]);
    } else {
      const int g = f - 1;
      const int n = g * Hn + w * 32 + l31;
#pragma unroll
      for (int j = 0; j < 8; ++j) v8[j] = f2bf(Whh[n * Hn + k0 + j]);
    }
  } else {
    const int kk = gi - 32;
    const int cbase = kk * 16 + half * 8;
    if (f == 0) {
#pragma unroll
      for (int j = 0; j < 8; ++j) v8[j] = 0;
    } else {
      const int g = f - 1;
      const int n = g * Hn + w * 32 + l31;
#pragma unroll
      for (int j = 0; j < 8; ++j) {
        const int c = cbase + j;
        float v = 0.0f;
        if (c < 64) v = Wih[n * INn + 3 + c];
        else if (c == 64) v = Wih[n * INn + 0];
        else if (c == 65) v = Wih[n * INn + 1];
        else if (c == 67) v = Wih[n * INn + 67];
        v8[j] = f2bf(v);
      }
    }
  }
  unsigned short* dst = us + (size_t)idx * 8;
#pragma unroll
  for (int j = 0; j < 8; ++j) dst[j] = v8[j];
}

// Persistent recurrent kernel: each block owns 32 batch rows for all 256 steps.
// 16 waves (1024 threads): 4 independent load-chains per SIMD instead of 2.
// Per-wave groups are 5 fragments; R5's 2-buffer rotation; R9's per-block
// phase rotation of the commutative group sweep.
__launch_bounds__(NTHREADS, 1)
__global__ void lstm_seq(const float* __restrict__ noise, const float* __restrict__ cluster,
                         const float* __restrict__ gap, const float* __restrict__ Wih,
                         const float* __restrict__ bih, const float* __restrict__ bhh,
                         const float* __restrict__ b1p, const float* __restrict__ W2p,
                         const float* __restrict__ b2p,
                         const unsigned short* __restrict__ us,
                         float* __restrict__ out) {
  __shared__ __align__(16) unsigned short hA[MB * Hn];      // 32 KB, swizzled A-layout
  __shared__ __align__(16) unsigned short extA[MB * 128];   // 8 KB, swizzled
  __shared__ float partial[NWAVE][MB];
  __shared__ float dp_lds[MB];

  const int tid = threadIdx.x;
  const int w = tid >> 6;          // 0..15
  const int lane = tid & 63;
  const int l31 = lane & 31;
  const int half = lane >> 5;
  const int r0 = blockIdx.x * MB;
  const int cb = w * 32;           // this wave's 32 hidden columns
  const int c0 = cb + l31;

  // phase rotation: blocks on the same XCD (bid%8 fixed) get staggered starts
  const int koff = (((blockIdx.x >> 3) & 15) * NGRP) >> 4;  // 0..34

  short8 zero8 = {0, 0, 0, 0, 0, 0, 0, 0};
  for (int i = tid; i < MB * Hn / 8; i += NTHREADS) ((short8*)hA)[i] = zero8;
  for (int i = tid; i < MB * 128 / 8; i += NTHREADS) ((short8*)extA)[i] = zero8;

  float biasv[4], wih2[4];
#pragma unroll
  for (int g = 0; g < 4; ++g) {
    int n = g * Hn + cb + l31;
    biasv[g] = bih[n] + bhh[n];
    wih2[g] = Wih[n * INn + 2];
  }
  const float b1v0 = b1p[c0];
  const float w2v0 = W2p[c0];
  const float b2v = b2p[0];
  const float clusf = cluster[r0 + (tid & 31)];

  // per-lane base of this wave's weight stream (short8 units)
  const short8* const ws = (const short8*)us + (size_t)w * WAVE_S8 + lane;

  // stage extras for t = 0 (512 threads cover the 32x64 noise tile)
  if (tid < 512) {
    const int row = tid >> 4, kq = (tid & 15) << 2;
    const float4 v = *(const float4*)(noise + ((size_t)(r0 + row) * Tn + 0) * NZ + kq);
    ushort4 hb;
    hb.x = f2bf(v.x); hb.y = f2bf(v.y); hb.z = f2bf(v.z); hb.w = f2bf(v.w);
    *(ushort4*)((char*)extA + row * 256 + ((kq << 1) ^ ((row & 15) << 4))) = hb;
    if (tid < MB) {
      const size_t gb = ((size_t)(r0 + tid) * (Tn + 1) + 0) * 2;
      ushort4 hg;
      hg.x = f2bf(gap[gb]); hg.y = f2bf(gap[gb + 1]); hg.z = 0; hg.w = f2bf(clusf);
      *(ushort4*)((char*)extA + tid * 256 + (128 ^ ((tid & 15) << 4))) = hg;
    }
  }

  float c_reg[16];
#pragma unroll
  for (int q = 0; q < 16; ++q) c_reg[q] = 0.f;

  __syncthreads();

  for (int t = 0; t <= Tn; ++t) {
    floatx16 zacc;
    floatx16 acc[4];
#pragma unroll
    for (int q = 0; q < 16; ++q) zacc[q] = 0.f;
#pragma unroll
    for (int g = 0; g < 4; ++g)
#pragma unroll
      for (int q = 0; q < 16; ++q) acc[g][q] = 0.f;

    // rotated group index (wave-uniform)
    auto wgrp = [&](int g) -> int {
      int x = g + koff;
      return (x >= NGRP) ? (x - NGRP) : x;
    };
    // load the 5 fragments of rotated group g into registers
    auto ldgrp = [&](int g, short8(&b)[FRAGS]) {
      const short8* p = ws + wgrp(g) * (FRAGS * 64);
#pragma unroll
      for (int f = 0; f < FRAGS; ++f) b[f] = p[f * 64];
    };
    // branchless A-fragment fetch + 5 MFMAs for rotated group g
    auto consume = [&](int g, const short8(&b)[FRAGS]) {
      const int gw = wgrp(g);
      const int isH = (gw < 32) ? 1 : 0;
      const int gg = isH ? gw : (gw - 32);
      const int k0 = (gg << 4) + (half << 3);
      const int rsh = isH ? 10 : 8;
      const int msk = isH ? l31 : (l31 & 15);
      const char* base = isH ? (const char*)hA : (const char*)extA;
      const short8 a = *(const short8*)(base + (l31 << rsh) + ((k0 << 1) ^ (msk << 4)));
      zacc   = __builtin_amdgcn_mfma_f32_32x32x16_bf16(a, b[0], zacc, 0, 0, 0);
      acc[0] = __builtin_amdgcn_mfma_f32_32x32x16_bf16(a, b[1], acc[0], 0, 0, 0);
      acc[1] = __builtin_amdgcn_mfma_f32_32x32x16_bf16(a, b[2], acc[1], 0, 0, 0);
      acc[2] = __builtin_amdgcn_mfma_f32_32x32x16_bf16(a, b[3], acc[2], 0, 0, 0);
      acc[3] = __builtin_amdgcn_mfma_f32_32x32x16_bf16(a, b[4], acc[3], 0, 0, 0);
    };

    short8 bufA[FRAGS], bufB[FRAGS];
    ldgrp(0, bufA);
    for (int ii = 0; ii < 18; ++ii) {
      const int g0 = 2 * ii;
      ldgrp(g0 + 1, bufB);
      consume(g0, bufA);
      ldgrp(g0 + 2, bufA);   // g0+2 <= 36 always
      consume(g0 + 1, bufB);
    }
    consume(36, bufA);

    // z finish + dp partials
    {
      float part[16];
#pragma unroll
      for (int q = 0; q < 16; ++q)
        part[q] = ftanh(zacc[q] + b1v0) * w2v0;
#pragma unroll
      for (int m = 1; m <= 16; m <<= 1)
#pragma unroll
        for (int q = 0; q < 16; ++q) part[q] += __shfl_xor(part[q], m, 64);
      if (l31 == 0) {
#pragma unroll
        for (int q = 0; q < 16; ++q)
          partial[w][(q & 3) + ((q >> 2) << 3) + (half << 2)] = part[q];
      }
    }

    __syncthreads();  // B1: partial complete; all reads of hA/extA complete

    if (tid < MB) {
      float ssum = b2v;
#pragma unroll
      for (int ww = 0; ww < NWAVE; ++ww) ssum += partial[ww][tid];
      const float dpv = DPRv * ftanh(ssum);
      dp_lds[tid] = dpv;
      const size_t gb = ((size_t)(r0 + tid) * (Tn + 1) + t) * 2;
      const float g0 = gap[gb], g1 = gap[gb + 1];
      float* op = out + ((size_t)(r0 + tid) * (Tn + 1) + t) * 3;
      op[0] = g0; op[1] = g1; op[2] = dpv;
    }
    if (t < Tn - 1 && tid < 512) {
      const int row = tid >> 4, kq = (tid & 15) << 2;
      const float4 v = *(const float4*)(noise + ((size_t)(r0 + row) * Tn + (t + 1)) * NZ + kq);
      ushort4 hb;
      hb.x = f2bf(v.x); hb.y = f2bf(v.y); hb.z = f2bf(v.z); hb.w = f2bf(v.w);
      *(ushort4*)((char*)extA + row * 256 + ((kq << 1) ^ ((row & 15) << 4))) = hb;
      if (tid < MB) {
        const size_t gb = ((size_t)(r0 + tid) * (Tn + 1) + (t + 1)) * 2;
        ushort4 hg;
        hg.x = f2bf(gap[gb]); hg.y = f2bf(gap[gb + 1]); hg.z = 0; hg.w = f2bf(clusf);
        *(ushort4*)((char*)extA + tid * 256 + (128 ^ ((tid & 15) << 4))) = hg;
      }
    }
    __syncthreads();  // B2: dp_lds visible; hA safe to overwrite

    if (t < Tn) {
      float dpv[16];
#pragma unroll
      for (int q = 0; q < 16; ++q)
        dpv[q] = dp_lds[(q & 3) + ((q >> 2) << 3) + (half << 2)];
      const int colb = (cb + l31) << 1;
#pragma unroll
      for (int q = 0; q < 16; ++q) {
        const float gi = acc[0][q] + biasv[0] + dpv[q] * wih2[0];
        const float gf = acc[1][q] + biasv[1] + dpv[q] * wih2[1];
        const float gg = acc[2][q] + biasv[2] + dpv[q] * wih2[2];
        const float go = acc[3][q] + biasv[3] + dpv[q] * wih2[3];
        float cv = c_reg[q];
        cv = fsig(gf) * cv + fsig(gi) * ftanh(gg);
        const float hv = fsig(go) * ftanh(cv);
        c_reg[q] = cv;
        const int r = (q & 3) + ((q >> 2) << 3) + (half << 2);
        *(unsigned short*)((char*)hA + (r << 10) + (colb ^ (r << 4))) = f2bf(hv);
      }
    }
    __syncthreads();  // B3: hA ready for next step
  }
}

extern "C" void kernel_launch(void* const* d_in, const int* in_sizes, int n_in,
                              void* d_out, int out_size, void* d_ws, size_t ws_size,
                              hipStream_t stream) {
  const float* noise   = (const float*)d_in[0];
  const float* cluster = (const float*)d_in[1];
  const float* gap     = (const float*)d_in[2];
  const float* Wih     = (const float*)d_in[3];
  const float* Whh     = (const float*)d_in[4];
  const float* bih     = (const float*)d_in[5];
  const float* bhh     = (const float*)d_in[6];
  const float* W1      = (const float*)d_in[7];
  const float* b1      = (const float*)d_in[8];
  const float* W2      = (const float*)d_in[9];
  const float* b2      = (const float*)d_in[10];

  unsigned short* us = (unsigned short*)d_ws;  // 3.03 MB packed stream

  prep_pack<<<(STREAM_SHORTS / 8 + 255) / 256, 256, 0, stream>>>(Wih, Whh, W1, us);
  lstm_seq<<<NBLK, NTHREADS, 0, stream>>>(noise, cluster, gap, Wih, bih, bhh, b1, W2, b2,
                                          us, (float*)d_out);
}